// Round 4
// baseline (253.360 us; speedup 1.0000x reference)
//
#include <hip/hip_runtime.h>
#include <hip/hip_bf16.h>

typedef short short8 __attribute__((ext_vector_type(8)));
typedef float f32x4  __attribute__((ext_vector_type(4)));

#define N_SEQ 8192
#define D_CH  512

constexpr int XLDS_B    = 8192;             // x ring: 1024 slots x 4 batches x 2B
constexpr int TSTRIDE   = 272;              // per reversed-t copy (bank spread)
constexpr int TLDS_B    = 8 * TSTRIDE;      // 2176
constexpr int WAVE_LDS  = XLDS_B + TLDS_B;  // 10368
constexpr int BLOCK_LDS = 2 * WAVE_LDS;     // 20736 (2 waves/block)

__device__ __forceinline__ unsigned short f32_to_bf16_bits(float f) {
    union { float f; unsigned int u; } v; v.f = f;
    unsigned int u = v.u;
    unsigned int r = u + 0x7FFFu + ((u >> 16) & 1u);   // RNE
    return (unsigned short)(r >> 16);
}

// gelu tanh-approx: y = v * (1 - 1/(exp2(K1*v + K2*v^3) + 1))
__device__ __forceinline__ float gelu_f(float v) {
  float w = v * (2.3022031f + 0.10294296f * v * v);
  float e = __builtin_amdgcn_exp2f(w);
  float r = __builtin_amdgcn_rcpf(e + 1.0f);
  return v - v * r;
}

// ---------------- pre-pass: transpose + cast to bf16 ----------------
__global__ __launch_bounds__(256) void transpose_cast_kernel(
    const float* __restrict__ x, const float* __restrict__ t,
    unsigned short* __restrict__ xT, unsigned short* __restrict__ tT) {
  __shared__ float tile[64][65];
  int blk = blockIdx.x;
  int bat = blk >> 10;
  int rem = blk & 1023;
  int i0 = (rem >> 3) << 6;
  int d0 = (rem & 7) << 6;
  const float* src; unsigned short* dst;
  if (bat < 4) { src = x + (size_t)bat * N_SEQ * D_CH; dst = xT + (size_t)bat * D_CH * N_SEQ; }
  else         { src = t;                              dst = tT; }
  int tx = threadIdx.x & 63, ty = threadIdx.x >> 6;
  #pragma unroll
  for (int r = ty; r < 64; r += 4)
    tile[r][tx] = src[(size_t)(i0 + r) * D_CH + (d0 + tx)];
  __syncthreads();
  #pragma unroll
  for (int r = ty; r < 64; r += 4)
    dst[(size_t)(d0 + r) * N_SEQ + (i0 + tx)] = f32_to_bf16_bits(tile[tx][r]);
}

// ---------------- output transpose: (d,b,i) -> (b,i,d) ----------------
__global__ __launch_bounds__(256) void transpose_out_kernel(
    const float* __restrict__ src, float* __restrict__ dst) {
  __shared__ float tile[64][65];
  int blk = blockIdx.x;
  int b   = blk >> 10;
  int rem = blk & 1023;
  int d0 = (rem & 7) << 6;
  int i0 = (rem >> 3) << 6;
  int tx = threadIdx.x & 63, ty = threadIdx.x >> 6;
  #pragma unroll
  for (int r = ty; r < 64; r += 4)
    tile[r][tx] = src[((size_t)(d0 + r) * 4 + b) * N_SEQ + i0 + tx];
  __syncthreads();
  #pragma unroll
  for (int r = ty; r < 64; r += 4)
    dst[((size_t)b * N_SEQ + i0 + r) * D_CH + d0 + tx] = tile[tx][r];
}

// ---------------- main kernel ----------------
// Block = (d, pair p): 2 waves, strips {p, 7-p}. Each wave takes half the
// lag-range (K-split) of BOTH strips -> exactly 144 iters/wave. Partial accs
// combined via LDS reduction (aliases dead rings).
// x ring layout: slot s, batch b at byte ((s>>3)<<6)|(b<<4)|((s&7)<<1); with
// staging lane uLin=(lane&3)|((lane>>4)<<2), b=(lane>>2)&3 the dst is exactly
// ringbase + 4*lane -> global_load_lds-compatible.
template<int DMAJOR>
__global__ __launch_bounds__(128) void tno_conv_kernel(
    const unsigned short* __restrict__ xT, const unsigned short* __restrict__ tT,
    float* __restrict__ outp) {
  __shared__ __align__(16) char lds_all[BLOCK_LDS];
  const int tid  = threadIdx.x;
  const int wv   = tid >> 6;
  const int lane = tid & 63;
  const int blk  = blockIdx.x;
  const int d    = blk >> 2;
  const int pr   = blk & 3;

  // MFMA lane constants
  const int m      = lane & 15;
  const int kb     = (lane >> 4) << 3;
  const int bcol   = m & 3;
  const int sl     = m >> 2;
  const int rA     = m & 7;
  const int aConst = kb - (m & 8);
  char* ldsW  = lds_all + wv * WAVE_LDS;
  char* ldsTb = ldsW + XLDS_B + rA * TSTRIDE;
  // t staging lane mapping
  const int stJ  = lane & 31;
  const int stR0 = (lane >> 5) << 2;
  char* ldsTw0 = ldsW + XLDS_B + (stR0 + 0) * TSTRIDE;
  char* ldsTw1 = ldsW + XLDS_B + (stR0 + 1) * TSTRIDE;
  char* ldsTw2 = ldsW + XLDS_B + (stR0 + 2) * TSTRIDE;
  char* ldsTw3 = ldsW + XLDS_B + (stR0 + 3) * TSTRIDE;
  const unsigned short* tTd = tT + ((size_t)d << 13);
  // x staging lane mapping (lane-linear LDS dst)
  const int uLin = (lane & 3) | ((lane >> 4) << 2);
  const int sb   = (lane >> 2) & 3;
  const unsigned short* xlaneB = xT + (((size_t)sb * D_CH + d) << 13) + (uLin << 1);

  typedef __attribute__((address_space(3))) unsigned int lds_u32;
  typedef const __attribute__((address_space(1))) unsigned int glb_u32;

  const int strips[2] = { pr, 7 - pr };

  #pragma unroll 1
  for (int si = 0; si < 2; ++si) {
    const int strip = strips[si];
    const int base  = strip << 10;
    const int nTot  = (strip << 5) + 32;   // total iters for this strip
    const int n0    = nTot >> 1;           // wave0 share (even)
    const int ws = -32 + ((wv ? n0 : 0) << 5);          // first l
    const int we = -32 + ((wv ? nTot : n0) << 5);       // exclusive bound

    f32x4 acc[4][4];
    #pragma unroll
    for (int g = 0; g < 4; ++g)
      #pragma unroll
      for (int k = 0; k < 4; ++k)
        acc[g][k] = (f32x4){0.f, 0.f, 0.f, 0.f};

    // ---- t prologue: stage values [ws-32, ws+63] into all 8 copies
    #pragma unroll 1
    for (int ls = ws - 96; ls <= ws - 32; ls += 32) {
      int idx = ls + 64 + stJ;
      unsigned short v = 0;
      if (idx >= 0 && idx < N_SEQ) v = tTd[idx];
      *(unsigned short*)(ldsTw0 + ((((stR0 + 0) - idx) & 127) << 1)) = v;
      *(unsigned short*)(ldsTw1 + ((((stR0 + 1) - idx) & 127) << 1)) = v;
      *(unsigned short*)(ldsTw2 + ((((stR0 + 2) - idx) & 127) << 1)) = v;
      *(unsigned short*)(ldsTw3 + ((((stR0 + 3) - idx) & 127) << 1)) = v;
    }
    // t prefetch: values [ws+64, ws+95]
    const unsigned short* tpv = tTd + (ws + 64 + stJ);
    int tguard = ws + 64 + stJ;
    unsigned int tvc = (tguard < N_SEQ) ? (unsigned int)(*tpv) : 0u;
    tpv += 32; tguard += 32;

    // ---- x prologue: rows [base-ws, base-ws+1023] (31 steps of 32 rows)
    const unsigned short* xsp = xlaneB + (base - ws + 960);
    #pragma unroll 1
    for (int j = 0; j < 31; ++j) {
      int R  = base - ws + 960 - (j << 5);
      int rb = (R & 1023) << 3;
      if (R >= 0)
        __builtin_amdgcn_global_load_lds((glb_u32*)xsp, (lds_u32*)(ldsW + rb), 4, 0, 0);
      else
        *(unsigned int*)(ldsW + rb + (lane << 2)) = 0u;
      xsp -= 32;
    }
    // xsp now = xlaneB + base - ws - 32  (first in-loop stage)
    asm volatile("s_waitcnt vmcnt(0)" ::: "memory");

    // ---- loop state
    int aC = ((aConst - ws - 32) & 127) << 1;
    short8 af0 = *(const short8*)(ldsTb + ((aC + 64) & 255));
    short8 af1 = *(const short8*)(ldsTb + ((aC + 32) & 255));
    int xo[4];
    #pragma unroll
    for (int g = 0; g < 4; ++g)
      xo[g] = ((((base + ((((g << 2) + sl) << 6) + kb) - ws) & 1023) << 3) | (bcol << 4));
    int tw0 = (((stR0 + 0) - (ws + 64 + stJ)) & 127) << 1;
    int tw1 = (((stR0 + 1) - (ws + 64 + stJ)) & 127) << 1;
    int tw2 = (((stR0 + 2) - (ws + 64 + stJ)) & 127) << 1;
    int tw3 = (((stR0 + 3) - (ws + 64 + stJ)) & 127) << 1;
    int l = ws;

#define CONV_ITER(GMIN)                                                          \
  {                                                                              \
    asm volatile("s_waitcnt vmcnt(31)" ::: "memory");                            \
    short8 af2 = *(const short8*)(ldsTb + aC);                                   \
    short8 af3 = *(const short8*)(ldsTb + ((aC - 32) & 255));                    \
    unsigned int tvn = 0;                                                        \
    if (tguard < N_SEQ) tvn = (unsigned int)(*tpv);                              \
    { int R  = base - l - 32;                                                    \
      int rb = (R & 1023) << 3;                                                  \
      if (R >= 0)                                                                \
        __builtin_amdgcn_global_load_lds((glb_u32*)xsp, (lds_u32*)(ldsW + rb), 4, 0, 0); \
      else                                                                       \
        *(unsigned int*)(ldsW + rb + (lane << 2)) = 0u;                          \
    }                                                                            \
    _Pragma("unroll")                                                            \
    for (int g = 0; g < 4; ++g) {                                                \
      if (g >= (GMIN)) {                                                         \
        short8 bf = *(const short8*)(ldsW + xo[g]);                              \
        acc[g][0] = __builtin_amdgcn_mfma_f32_16x16x32_bf16(af0, bf, acc[g][0], 0, 0, 0); \
        acc[g][1] = __builtin_amdgcn_mfma_f32_16x16x32_bf16(af1, bf, acc[g][1], 0, 0, 0); \
        acc[g][2] = __builtin_amdgcn_mfma_f32_16x16x32_bf16(af2, bf, acc[g][2], 0, 0, 0); \
        acc[g][3] = __builtin_amdgcn_mfma_f32_16x16x32_bf16(af3, bf, acc[g][3], 0, 0, 0); \
        xo[g] = (xo[g] - 256) & 8191;                                            \
      }                                                                          \
    }                                                                            \
    { unsigned short tvs = (unsigned short)tvc;                                  \
      *(unsigned short*)(ldsTw0 + tw0) = tvs;                                    \
      *(unsigned short*)(ldsTw1 + tw1) = tvs;                                    \
      *(unsigned short*)(ldsTw2 + tw2) = tvs;                                    \
      *(unsigned short*)(ldsTw3 + tw3) = tvs;                                    \
    }                                                                            \
    tw0 = (tw0 - 64) & 255; tw1 = (tw1 - 64) & 255;                              \
    tw2 = (tw2 - 64) & 255; tw3 = (tw3 - 64) & 255;                              \
    tvc = tvn; tpv += 32; tguard += 32;                                          \
    af0 = af2; af1 = af3;                                                        \
    aC = (aC - 64) & 255;                                                        \
    xsp -= 32;                                                                   \
    l += 32;                                                                     \
  }

    { int hi = base + 224; if (hi > we) hi = we; while (l < hi) CONV_ITER(0) }
    { int hi = base + 480; if (hi > we) hi = we; while (l < hi) CONV_ITER(1) }
    { int hi = base + 736; if (hi > we) hi = we; while (l < hi) CONV_ITER(2) }
    { int hi = we;                               while (l < hi) CONV_ITER(3) }
#undef CONV_ITER

    // ---- cross-wave reduction (RED aliases dead rings), gelu, store
    __syncthreads();
    float* red = (float*)lds_all;
    if (wv == 0) {
      #pragma unroll
      for (int k = 0; k < 4; ++k) {
        *(f32x4*)(red + ((0 * 4 + k) << 8) + (lane << 2)) = acc[2][k];
        *(f32x4*)(red + ((1 * 4 + k) << 8) + (lane << 2)) = acc[3][k];
      }
    } else {
      #pragma unroll
      for (int k = 0; k < 4; ++k) {
        *(f32x4*)(red + 2048 + ((0 * 4 + k) << 8) + (lane << 2)) = acc[0][k];
        *(f32x4*)(red + 2048 + ((1 * 4 + k) << 8) + (lane << 2)) = acc[1][k];
      }
    }
    __syncthreads();

    float* op = outp + ((((size_t)d << 2) + bcol) << 13) + base + (sl << 6) + ((lane >> 4) << 2);

#define STORE_G(G, SRCOFF)                                                       \
    _Pragma("unroll")                                                            \
    for (int k = 0; k < 4; ++k) {                                                \
      f32x4 p = *(const f32x4*)(red + (SRCOFF) + (k << 8) + (lane << 2));        \
      f32x4 s = acc[G][k] + p;                                                   \
      _Pragma("unroll")                                                          \
      for (int r = 0; r < 4; ++r) {                                              \
        float y = gelu_f(s[r]);                                                  \
        if (DMAJOR) {                                                            \
          op[((G) << 8) + (k << 4) + r] = y;                                     \
        } else {                                                                 \
          int i = base + ((((G) << 2) + sl) << 6) + (k << 4) + ((lane >> 4) << 2) + r; \
          outp[(((size_t)bcol << 13) + (size_t)i) * D_CH + d] = y;               \
        }                                                                        \
      }                                                                          \
    }

    if (wv == 0) {
      STORE_G(0, 2048)
      STORE_G(1, 2048 + 1024)
    } else {
      STORE_G(2, 0)
      STORE_G(3, 1024)
    }
#undef STORE_G
    __syncthreads();   // rings reused by next strip's prologue
  }
}

extern "C" void kernel_launch(void* const* d_in, const int* in_sizes, int n_in,
                              void* d_out, int out_size, void* d_ws, size_t ws_size,
                              hipStream_t stream) {
  const float* x = (const float*)d_in[0];
  const float* t = (const float*)d_in[1];
  float* out = (float*)d_out;

  const size_t xT_elems = (size_t)4 * D_CH * N_SEQ;       // bf16
  const size_t tT_elems = (size_t)D_CH * N_SEQ;           // bf16
  unsigned short* xT = (unsigned short*)d_ws;
  unsigned short* tT = xT + xT_elems;
  float* ows = (float*)(tT + tT_elems);
  const size_t need = xT_elems * 2 + tT_elems * 2 + (size_t)4 * N_SEQ * D_CH * 4;
  const bool dmaj = (ws_size >= need);

  hipLaunchKernelGGL(transpose_cast_kernel, dim3(5 * 1024), dim3(256), 0, stream,
                     x, t, xT, tT);
  if (dmaj) {
    hipLaunchKernelGGL((tno_conv_kernel<1>), dim3(2048), dim3(128), 0, stream,
                       xT, tT, ows);
    hipLaunchKernelGGL(transpose_out_kernel, dim3(4096), dim3(256), 0, stream,
                       ows, out);
  } else {
    hipLaunchKernelGGL((tno_conv_kernel<0>), dim3(2048), dim3(128), 0, stream,
                       xT, tT, out);
  }
}

// Round 5
// 202.314 us; speedup vs baseline: 1.2523x; 1.2523x over previous
//
#include <hip/hip_runtime.h>
#include <hip/hip_bf16.h>

typedef short short8 __attribute__((ext_vector_type(8)));
typedef float f32x4  __attribute__((ext_vector_type(4)));

#define N_SEQ 8192
#define D_CH  512

constexpr int XSLOTS  = 2048;              // x ring slots (rows), 4 batches x 2B each
constexpr int XLDS_B  = XSLOTS * 8;        // 16384 B; byte(s,b) = ((s>>3)<<6)|(b<<4)|((s&7)<<1)
constexpr int TSTRIDE = 272;               // per reversed-t copy (bank spread)
constexpr int TLDS_B  = 8 * TSTRIDE;       // 2176 B
constexpr int ALL_LDS = XLDS_B + TLDS_B;   // 18560 B -> 8 blocks/CU

__device__ __forceinline__ unsigned short f32_to_bf16_bits(float f) {
    union { float f; unsigned int u; } v; v.f = f;
    unsigned int u = v.u;
    unsigned int r = u + 0x7FFFu + ((u >> 16) & 1u);   // RNE
    return (unsigned short)(r >> 16);
}

// gelu tanh-approx: y = v * (1 - 1/(exp2(K1*v + K2*v^3) + 1))
__device__ __forceinline__ float gelu_f(float v) {
  float w = v * (2.3022031f + 0.10294296f * v * v);
  float e = __builtin_amdgcn_exp2f(w);
  float r = __builtin_amdgcn_rcpf(e + 1.0f);
  return v - v * r;
}

// ---------------- pre-pass: transpose + cast to bf16 ----------------
__global__ __launch_bounds__(256) void transpose_cast_kernel(
    const float* __restrict__ x, const float* __restrict__ t,
    unsigned short* __restrict__ xT, unsigned short* __restrict__ tT) {
  __shared__ float tile[64][65];
  int blk = blockIdx.x;
  int bat = blk >> 10;
  int rem = blk & 1023;
  int i0 = (rem >> 3) << 6;
  int d0 = (rem & 7) << 6;
  const float* src; unsigned short* dst;
  if (bat < 4) { src = x + (size_t)bat * N_SEQ * D_CH; dst = xT + (size_t)bat * D_CH * N_SEQ; }
  else         { src = t;                              dst = tT; }
  int tx = threadIdx.x & 63, ty = threadIdx.x >> 6;
  #pragma unroll
  for (int r = ty; r < 64; r += 4)
    tile[r][tx] = src[(size_t)(i0 + r) * D_CH + (d0 + tx)];
  __syncthreads();
  #pragma unroll
  for (int r = ty; r < 64; r += 4)
    dst[(size_t)(d0 + r) * N_SEQ + (i0 + tx)] = f32_to_bf16_bits(tile[tx][r]);
}

// ---------------- output transpose: (d,b,i) -> (b,i,d) ----------------
__global__ __launch_bounds__(256) void transpose_out_kernel(
    const float* __restrict__ src, float* __restrict__ dst) {
  __shared__ float tile[64][65];
  int blk = blockIdx.x;
  int b   = blk >> 10;
  int rem = blk & 1023;
  int d0 = (rem & 7) << 6;
  int i0 = (rem >> 3) << 6;
  int tx = threadIdx.x & 63, ty = threadIdx.x >> 6;
  #pragma unroll
  for (int r = ty; r < 64; r += 4)
    tile[r][tx] = src[((size_t)(d0 + r) * 4 + b) * N_SEQ + i0 + tx];
  __syncthreads();
  #pragma unroll
  for (int r = ty; r < 64; r += 4)
    dst[((size_t)b * N_SEQ + i0 + r) * D_CH + d0 + tx] = tile[tx][r];
}

// ---------------- main kernel ----------------
// 1 wave/block. blk = pr*512 + d  (all 4 pair-blocks of channel d on XCD d%8).
// Wave does strips {pr, 7-pr} sequentially (288 iters total), lag-blocks l
// DESCENDING from base+960 to -32. x ring (2048 slots) = read frame (1024)
// + 7-iter staged-ahead margin; per-iter counted vmcnt(14) never drains the
// pipeline. t values flow through an 8-deep register pipe tv[8].
template<int DMAJOR>
__global__ __launch_bounds__(64) void tno_conv_kernel(
    const unsigned short* __restrict__ xT, const unsigned short* __restrict__ tT,
    float* __restrict__ outp) {
  __shared__ __align__(16) char lds[ALL_LDS];
  const int lane = threadIdx.x & 63;
  const int blk  = blockIdx.x;
  const int d    = blk & 511;
  const int pr   = blk >> 9;

  // MFMA lane constants
  const int m      = lane & 15;
  const int kb     = (lane >> 4) << 3;
  const int bcol   = m & 3;
  const int sl     = m >> 2;
  const int rA     = m & 7;
  const int aConst = kb - (m & 8);
  char* ldsX = lds;
  char* ldsT = lds + XLDS_B;
  const char* tb = ldsT + rA * TSTRIDE;
  // t staging lane mapping
  const int stJ  = lane & 31;
  const int stR0 = (lane >> 5) << 2;
  const unsigned short* tTd = tT + ((size_t)d << 13);
  // x staging lane mapping (LDS dst byte = 4*lane, matches ring layout)
  const int uLin = (lane & 3) | ((lane >> 4) << 2);
  const int sb   = (lane >> 2) & 3;
  const unsigned short* xlaneB = xT + (((size_t)sb * D_CH + d) << 13) + (uLin << 1);

  typedef __attribute__((address_space(3))) unsigned int lds_u32;
  typedef const __attribute__((address_space(1))) unsigned int glb_u32;

  #pragma unroll 1
  for (int si = 0; si < 2; ++si) {
    const int strip = si ? (7 - pr) : pr;
    const int base  = strip << 10;
    const int l_hi  = base + 960;        // first (highest) lag-block

    f32x4 acc[4][4];
    #pragma unroll
    for (int g = 0; g < 4; ++g)
      #pragma unroll
      for (int k = 0; k < 4; ++k)
        acc[g][k] = (f32x4){0.f, 0.f, 0.f, 0.f};

    // drain old in-flight gloads before rewriting the rings
    asm volatile("s_waitcnt vmcnt(0)" ::: "memory");

    // t prologue loads first (their consumption then never drains x queue)
    unsigned short tp0 = tTd[l_hi + 32 + stJ];   // values [l_hi+32, l_hi+63]
    unsigned short tp1 = tTd[l_hi + stJ];        // [l_hi, l_hi+31]
    unsigned short tp2 = tTd[l_hi - 32 + stJ];   // [l_hi-32, l_hi-1]
    asm volatile("" ::: "memory");

    // x prologue: rows [-960,-1] zero (slots 1088..2047), rows [0,287] gload
    #pragma unroll
    for (int j = 0; j < 30; ++j) {
      int by = (1088 + 32 * j) << 3;
      *(unsigned int*)(ldsX + by + (lane << 2)) = 0u;
    }
    #pragma unroll
    for (int j = 0; j < 9; ++j) {
      int R = 32 * j;
      __builtin_amdgcn_global_load_lds((glb_u32*)(xlaneB + R),
                                       (lds_u32*)(ldsX + (R << 3)), 4, 0, 0);
    }
    asm volatile("" ::: "memory");

    // t prologue writes (compiler waits only the 3 t loads; 9 x stay in flight)
    #pragma unroll
    for (int c = 0; c < 4; ++c) {
      int r = stR0 + c;
      char* cw = ldsT + r * TSTRIDE;
      *(unsigned short*)(cw + (((r - (l_hi + 32 + stJ)) & 127) << 1)) = tp0;
      *(unsigned short*)(cw + (((r - (l_hi      + stJ)) & 127) << 1)) = tp1;
      *(unsigned short*)(cw + (((r - (l_hi - 32 + stJ)) & 127) << 1)) = tp2;
    }

    // t register pipe prefill: tv[u] = value written at iter u
    unsigned short tv[8];
    #pragma unroll
    for (int u = 0; u < 8; ++u)
      tv[u] = tTd[l_hi - 32 * u - 63 + stJ];   // idx in [673, 8096] always

    // ---- loop state (all incremental) ----
    int aC = ((aConst - l_hi) & 127) << 1;                 // k=0 byte at current l
    short8 af2 = *(const short8*)(tb + ((aC - 64) & 255)); // prime k=2
    short8 af3 = *(const short8*)(tb + ((aC - 96) & 255)); // prime k=3
    int xo[4];
    #pragma unroll
    for (int g = 0; g < 4; ++g)
      xo[g] = ((((base + ((((g << 2) + sl) << 6) + kb) - l_hi) & 2047) << 3) | (bcol << 4));
    int twb[4];
    #pragma unroll
    for (int c = 0; c < 4; ++c)
      twb[c] = (((stR0 + c) - (l_hi - 63 + stJ)) & 127) << 1;
    int tgi = l_hi - 319 + stJ;          // next t load idx (8 iters ahead)
    const unsigned short* xsp = xlaneB + 288;   // next gload rows [288,319]
    int wb = 288 << 3;

#define CONV_ITER(GMIN, U)                                                       \
  {                                                                              \
    asm volatile("s_waitcnt vmcnt(14)" ::: "memory");                            \
    short8 af0 = *(const short8*)(tb + aC);                                      \
    short8 af1 = *(const short8*)(tb + ((aC - 32) & 255));                       \
    __builtin_amdgcn_global_load_lds((glb_u32*)xsp, (lds_u32*)(ldsX + wb), 4, 0, 0); \
    __builtin_amdgcn_s_setprio(1);                                               \
    _Pragma("unroll")                                                            \
    for (int g = 0; g < 4; ++g) {                                                \
      if (g >= (GMIN)) {                                                         \
        short8 bf = *(const short8*)(ldsX + xo[g]);                              \
        acc[g][0] = __builtin_amdgcn_mfma_f32_16x16x32_bf16(af0, bf, acc[g][0], 0, 0, 0); \
        acc[g][1] = __builtin_amdgcn_mfma_f32_16x16x32_bf16(af1, bf, acc[g][1], 0, 0, 0); \
        acc[g][2] = __builtin_amdgcn_mfma_f32_16x16x32_bf16(af2, bf, acc[g][2], 0, 0, 0); \
        acc[g][3] = __builtin_amdgcn_mfma_f32_16x16x32_bf16(af3, bf, acc[g][3], 0, 0, 0); \
      }                                                                          \
      xo[g] = (xo[g] + 256) & 16383;                                             \
    }                                                                            \
    __builtin_amdgcn_s_setprio(0);                                               \
    { unsigned short tvs = tv[U];                                                \
      _Pragma("unroll")                                                          \
      for (int c = 0; c < 4; ++c) {                                              \
        *(unsigned short*)(ldsT + (stR0 + c) * TSTRIDE + twb[c]) = tvs;          \
        twb[c] = (twb[c] + 64) & 255;                                            \
      }                                                                          \
    }                                                                            \
    { unsigned short v = 0;                                                      \
      if (tgi >= 0) v = tTd[tgi];                                                \
      tv[U] = v; tgi -= 32; }                                                    \
    af2 = af0; af3 = af1;                                                        \
    aC = (aC + 64) & 255;                                                        \
    xsp += 32;                                                                   \
    wb = (wb + 256) & 16383;                                                     \
  }

#define PH8(GMIN)                                                                \
    { _Pragma("unroll")                                                          \
      for (int u = 0; u < 8; ++u) CONV_ITER(GMIN, u) }

    PH8(3)                                  // l = base+960 .. base+736
    PH8(2)                                  // l = base+704 .. base+480
    PH8(1)                                  // l = base+448 .. base+224
    const int n0 = (strip << 2) + 1;        // (32*strip+8)/8 blocks of 8
    #pragma unroll 1
    for (int c8 = 0; c8 < n0; ++c8)
      PH8(0)                                // l = base+192 .. -32
#undef PH8
#undef CONV_ITER

    // ---- epilogue: gelu + store ----
    if (DMAJOR) {
      float* op = outp + ((((size_t)d << 2) + bcol) << 13) + base + (sl << 6) + ((lane >> 4) << 2);
      #pragma unroll
      for (int g = 0; g < 4; ++g)
        #pragma unroll
        for (int k = 0; k < 4; ++k)
          #pragma unroll
          for (int r = 0; r < 4; ++r)
            op[(g << 8) + (k << 4) + r] = gelu_f(acc[g][k][r]);
    } else {
      #pragma unroll
      for (int g = 0; g < 4; ++g)
        #pragma unroll
        for (int k = 0; k < 4; ++k)
          #pragma unroll
          for (int r = 0; r < 4; ++r) {
            int i = base + (((g << 2) + sl) << 6) + (k << 4) + ((lane >> 4) << 2) + r;
            outp[(((size_t)bcol << 13) + (size_t)i) * D_CH + d] = gelu_f(acc[g][k][r]);
          }
    }
  }
}

extern "C" void kernel_launch(void* const* d_in, const int* in_sizes, int n_in,
                              void* d_out, int out_size, void* d_ws, size_t ws_size,
                              hipStream_t stream) {
  const float* x = (const float*)d_in[0];
  const float* t = (const float*)d_in[1];
  float* out = (float*)d_out;

  const size_t xT_elems = (size_t)4 * D_CH * N_SEQ;       // bf16
  const size_t tT_elems = (size_t)D_CH * N_SEQ;           // bf16
  unsigned short* xT = (unsigned short*)d_ws;
  unsigned short* tT = xT + xT_elems;
  float* ows = (float*)(tT + tT_elems);
  const size_t need = xT_elems * 2 + tT_elems * 2 + (size_t)4 * N_SEQ * D_CH * 4;
  const bool dmaj = (ws_size >= need);

  hipLaunchKernelGGL(transpose_cast_kernel, dim3(5 * 1024), dim3(256), 0, stream,
                     x, t, xT, tT);
  if (dmaj) {
    hipLaunchKernelGGL((tno_conv_kernel<1>), dim3(2048), dim3(64), 0, stream,
                       xT, tT, ows);
    hipLaunchKernelGGL(transpose_out_kernel, dim3(4096), dim3(256), 0, stream,
                       ows, out);
  } else {
    hipLaunchKernelGGL((tno_conv_kernel<0>), dim3(2048), dim3(64), 0, stream,
                       xT, tT, out);
  }
}

// Round 7
// 165.892 us; speedup vs baseline: 1.5273x; 1.2196x over previous
//
#include <hip/hip_runtime.h>
#include <hip/hip_bf16.h>

typedef short short8 __attribute__((ext_vector_type(8)));
typedef float f32x4  __attribute__((ext_vector_type(4)));

#define N_SEQ 8192
#define D_CH  512

constexpr int XSLOTS  = 1280;              // x ring slots (rows); live span <= 1280 proven
constexpr int XLDS_B  = XSLOTS * 8;        // 10240 B; byte(s,b) = s*8 + b*16 (s mult of 8)
constexpr int TSTRIDE = 272;               // per reversed-t copy (bank spread)
constexpr int TLDS_B  = 8 * TSTRIDE;       // 2176 B
constexpr int ALL_LDS = XLDS_B + TLDS_B;   // 12416 B -> 12 blocks/CU (3 waves/SIMD)

__device__ __forceinline__ unsigned short f32_to_bf16_bits(float f) {
    union { float f; unsigned int u; } v; v.f = f;
    unsigned int u = v.u;
    unsigned int r = u + 0x7FFFu + ((u >> 16) & 1u);   // RNE
    return (unsigned short)(r >> 16);
}

// gelu tanh-approx: y = v * (1 - 1/(exp2(K1*v + K2*v^3) + 1))
__device__ __forceinline__ float gelu_f(float v) {
  float w = v * (2.3022031f + 0.10294296f * v * v);
  float e = __builtin_amdgcn_exp2f(w);
  float r = __builtin_amdgcn_rcpf(e + 1.0f);
  return v - v * r;
}

// ---------------- pre-pass: transpose + cast to bf16 ----------------
__global__ __launch_bounds__(256) void transpose_cast_kernel(
    const float* __restrict__ x, const float* __restrict__ t,
    unsigned short* __restrict__ xT, unsigned short* __restrict__ tT) {
  __shared__ float tile[64][65];
  int blk = blockIdx.x;
  int bat = blk >> 10;
  int rem = blk & 1023;
  int i0 = (rem >> 3) << 6;
  int d0 = (rem & 7) << 6;
  const float* src; unsigned short* dst;
  if (bat < 4) { src = x + (size_t)bat * N_SEQ * D_CH; dst = xT + (size_t)bat * D_CH * N_SEQ; }
  else         { src = t;                              dst = tT; }
  int tx = threadIdx.x & 63, ty = threadIdx.x >> 6;
  #pragma unroll
  for (int r = ty; r < 64; r += 4)
    tile[r][tx] = src[(size_t)(i0 + r) * D_CH + (d0 + tx)];
  __syncthreads();
  #pragma unroll
  for (int r = ty; r < 64; r += 4)
    dst[(size_t)(d0 + r) * N_SEQ + (i0 + tx)] = f32_to_bf16_bits(tile[tx][r]);
}

// ---------------- output transpose: (d,b,i) -> (b,i,d) ----------------
__global__ __launch_bounds__(256) void transpose_out_kernel(
    const float* __restrict__ src, float* __restrict__ dst) {
  __shared__ float tile[64][65];
  int blk = blockIdx.x;
  int b   = blk >> 10;
  int rem = blk & 1023;
  int d0 = (rem & 7) << 6;
  int i0 = (rem >> 3) << 6;
  int tx = threadIdx.x & 63, ty = threadIdx.x >> 6;
  #pragma unroll
  for (int r = ty; r < 64; r += 4)
    tile[r][tx] = src[((size_t)(d0 + r) * 4 + b) * N_SEQ + i0 + tx];
  __syncthreads();
  #pragma unroll
  for (int r = ty; r < 64; r += 4)
    dst[((size_t)b * N_SEQ + i0 + r) * D_CH + d0 + tx] = tile[tx][r];
}

// ---------------- main kernel ----------------
// 1 wave/block; grid 4096: blk = sblk*512 + d, strip = 7 - sblk (longest first),
// XCD = d%8 shared by all 8 blocks of channel d. Lag-blocks l DESCEND from
// base+960 to -32 (32*strip+32 iters). x ring 1280 slots: read frame (1024
// rows) + 7-iter DMA margin; per-iter counted vmcnt(14) (2 vmem ops/iter).
// t values flow through an 8-deep register pipe tv[8] (static idx via unroll).
template<int DMAJOR>
__global__ __launch_bounds__(64, 3) void tno_conv_kernel(
    const unsigned short* __restrict__ xT, const unsigned short* __restrict__ tT,
    float* __restrict__ outp) {
  __shared__ __align__(16) char lds[ALL_LDS];
  const int lane = threadIdx.x & 63;
  const int blk  = blockIdx.x;
  const int d    = blk & 511;
  const int strip = 7 - (blk >> 9);
  const int base  = strip << 10;
  const int l_hi  = base + 960;

  // MFMA lane constants
  const int m      = lane & 15;
  const int kb     = (lane >> 4) << 3;
  const int bcol   = m & 3;
  const int sl     = m >> 2;
  const int rA     = m & 7;
  const int aConst = kb - (m & 8);
  char* ldsX = lds;
  char* ldsT = lds + XLDS_B;
  const char* tb = ldsT + rA * TSTRIDE;
  // t staging lane mapping
  const int stJ  = lane & 31;
  const int stR0 = (lane >> 5) << 2;
  const unsigned short* tTd = tT + ((size_t)d << 13);
  // x staging lane mapping (LDS dst byte = 4*lane within each 256B region)
  const int uLin = (lane & 3) | ((lane >> 4) << 2);
  const int sb   = (lane >> 2) & 3;
  const unsigned short* xlaneB = xT + (((size_t)sb * D_CH + d) << 13) + (uLin << 1);

  typedef __attribute__((address_space(3))) unsigned int lds_u32;
  typedef const __attribute__((address_space(1))) unsigned int glb_u32;

  f32x4 acc[4][4];
  #pragma unroll
  for (int g = 0; g < 4; ++g)
    #pragma unroll
    for (int k = 0; k < 4; ++k)
      acc[g][k] = (f32x4){0.f, 0.f, 0.f, 0.f};

  // t prologue loads first (their consumption never drains the x queue)
  unsigned short tp0 = tTd[l_hi + 32 + stJ];   // values [l_hi+32, l_hi+63]
  unsigned short tp1 = tTd[l_hi + stJ];        // [l_hi, l_hi+31]
  unsigned short tp2 = tTd[l_hi - 32 + stJ];   // [l_hi-32, l_hi-1]
  asm volatile("" ::: "memory");

  // x prologue: zero rows [-960,-1] (slots 320..1279), gload rows [0,255]
  {
    f32x4 z = (f32x4){0.f, 0.f, 0.f, 0.f};
    #pragma unroll
    for (int j = 0; j < 7; ++j)
      *(f32x4*)(ldsX + 2560 + (j << 10) + (lane << 4)) = z;
    *(unsigned long long*)(ldsX + 9728 + (lane << 3)) = 0ull;
    #pragma unroll
    for (int j = 0; j < 8; ++j)
      __builtin_amdgcn_global_load_lds((glb_u32*)(const void*)(xlaneB + (j << 5)),
                                       (lds_u32*)(void*)(ldsX + (j << 8)), 4, 0, 0);
  }
  asm volatile("" ::: "memory");

  // t prologue writes (stage values [l_hi-32, l_hi+63] into all 8 copies)
  #pragma unroll
  for (int c = 0; c < 4; ++c) {
    int r = stR0 + c;
    char* cw = ldsT + r * TSTRIDE;
    *(unsigned short*)(cw + (((r - (l_hi + 32 + stJ)) & 127) << 1)) = tp0;
    *(unsigned short*)(cw + (((r - (l_hi      + stJ)) & 127) << 1)) = tp1;
    *(unsigned short*)(cw + (((r - (l_hi - 32 + stJ)) & 127) << 1)) = tp2;
  }

  // t register pipe prefill: tv[u] = value written at iter u
  unsigned short tv[8];
  #pragma unroll
  for (int u = 0; u < 8; ++u)
    tv[u] = tTd[l_hi - 32 * u - 63 + stJ];   // idx in [673, 8096] for all strips

  asm volatile("s_waitcnt vmcnt(0)" ::: "memory");

  // ---- loop state (all incremental) ----
  int aC = ((aConst - l_hi) & 127) << 1;                 // k=0 byte at current l
  short8 af2 = *(const short8*)(tb + ((aC - 64) & 255)); // prime k=2
  short8 af3 = *(const short8*)(tb + ((aC - 96) & 255)); // prime k=3
  int xo[4];
  #pragma unroll
  for (int g = 0; g < 4; ++g) {
    int row = (base - l_hi) + (g << 8) + (sl << 6) + kb;   // in [-960, 24]
    int slot = row + ((row < 0) ? XSLOTS : 0);
    xo[g] = (slot << 3) + (bcol << 4);
  }
  int twb[4];
  #pragma unroll
  for (int c = 0; c < 4; ++c)
    twb[c] = (((stR0 + c) - (l_hi - 63 + stJ)) & 127) << 1;
  int tgi = l_hi - 319 + stJ;                  // next t load idx (8 iters ahead)
  const unsigned short* xsp = xlaneB + 256;    // next gload: rows [256,287]
  int wb = 256 << 3;                           // 2048

#define CONV_ITER(GMIN, U)                                                       \
  {                                                                              \
    asm volatile("s_waitcnt vmcnt(14)" ::: "memory");                            \
    short8 af0 = *(const short8*)(tb + aC);                                      \
    short8 af1 = *(const short8*)(tb + ((aC - 32) & 255));                       \
    __builtin_amdgcn_global_load_lds((glb_u32*)(const void*)xsp,                 \
        (lds_u32*)(void*)(ldsX + wb), 4, 0, 0);                                  \
    __builtin_amdgcn_s_setprio(1);                                               \
    _Pragma("unroll")                                                            \
    for (int g = 0; g < 4; ++g) {                                                \
      if (g >= (GMIN)) {                                                         \
        short8 bf = *(const short8*)(ldsX + xo[g]);                              \
        acc[g][0] = __builtin_amdgcn_mfma_f32_16x16x32_bf16(af0, bf, acc[g][0], 0, 0, 0); \
        acc[g][1] = __builtin_amdgcn_mfma_f32_16x16x32_bf16(af1, bf, acc[g][1], 0, 0, 0); \
        acc[g][2] = __builtin_amdgcn_mfma_f32_16x16x32_bf16(af2, bf, acc[g][2], 0, 0, 0); \
        acc[g][3] = __builtin_amdgcn_mfma_f32_16x16x32_bf16(af3, bf, acc[g][3], 0, 0, 0); \
      }                                                                          \
      xo[g] += 256; if (xo[g] >= XLDS_B) xo[g] -= XLDS_B;                        \
    }                                                                            \
    __builtin_amdgcn_s_setprio(0);                                               \
    { unsigned short tvs = tv[U];                                                \
      _Pragma("unroll")                                                          \
      for (int c = 0; c < 4; ++c) {                                              \
        *(unsigned short*)(ldsT + (stR0 + c) * TSTRIDE + twb[c]) = tvs;          \
        twb[c] = (twb[c] + 64) & 255;                                            \
      }                                                                          \
    }                                                                            \
    { int ti = (tgi < 0) ? 0 : tgi;                                              \
      unsigned short v = tTd[ti];          /* always issued: stable vmcnt */     \
      tv[U] = (tgi < 0) ? (unsigned short)0 : v;                                 \
      tgi -= 32; }                                                               \
    af2 = af0; af3 = af1;                                                        \
    aC = (aC + 64) & 255;                                                        \
    xsp += 32;                                                                   \
    wb += 256; if (wb >= XLDS_B) wb -= XLDS_B;                                   \
  }

#define PH8(GMIN)                                                                \
    { _Pragma("unroll")                                                          \
      for (int u = 0; u < 8; ++u) CONV_ITER(GMIN, u) }

  PH8(3)                                  // l = base+960 .. base+736
  PH8(2)                                  // l = base+704 .. base+480
  PH8(1)                                  // l = base+448 .. base+224
  const int n0 = (strip << 2) + 1;        // (32*strip+8)/8 blocks of 8
  #pragma unroll 1
  for (int c8 = 0; c8 < n0; ++c8)
    PH8(0)                                // l = base+192 .. -32
#undef PH8
#undef CONV_ITER

  // drain in-flight DMA so nothing lands in a successor block's LDS
  asm volatile("s_waitcnt vmcnt(0)" ::: "memory");

  // ---- epilogue: gelu + store ----
  if (DMAJOR) {
    float* op = outp + ((((size_t)d << 2) + bcol) << 13) + base + (sl << 6) + ((lane >> 4) << 2);
    #pragma unroll
    for (int g = 0; g < 4; ++g)
      #pragma unroll
      for (int k = 0; k < 4; ++k)
        #pragma unroll
        for (int r = 0; r < 4; ++r)
          op[(g << 8) + (k << 4) + r] = gelu_f(acc[g][k][r]);
  } else {
    #pragma unroll
    for (int g = 0; g < 4; ++g)
      #pragma unroll
      for (int k = 0; k < 4; ++k)
        #pragma unroll
        for (int r = 0; r < 4; ++r) {
          int i = base + (((g << 2) + sl) << 6) + (k << 4) + ((lane >> 4) << 2) + r;
          outp[(((size_t)bcol << 13) + (size_t)i) * D_CH + d] = gelu_f(acc[g][k][r]);
        }
  }
}

extern "C" void kernel_launch(void* const* d_in, const int* in_sizes, int n_in,
                              void* d_out, int out_size, void* d_ws, size_t ws_size,
                              hipStream_t stream) {
  const float* x = (const float*)d_in[0];
  const float* t = (const float*)d_in[1];
  float* out = (float*)d_out;

  const size_t xT_elems = (size_t)4 * D_CH * N_SEQ;       // bf16
  const size_t tT_elems = (size_t)D_CH * N_SEQ;           // bf16
  unsigned short* xT = (unsigned short*)d_ws;
  unsigned short* tT = xT + xT_elems;
  float* ows = (float*)(tT + tT_elems);
  const size_t need = xT_elems * 2 + tT_elems * 2 + (size_t)4 * N_SEQ * D_CH * 4;
  const bool dmaj = (ws_size >= need);

  hipLaunchKernelGGL(transpose_cast_kernel, dim3(5 * 1024), dim3(256), 0, stream,
                     x, t, xT, tT);
  if (dmaj) {
    hipLaunchKernelGGL((tno_conv_kernel<1>), dim3(4096), dim3(64), 0, stream,
                       xT, tT, ows);
    hipLaunchKernelGGL(transpose_out_kernel, dim3(4096), dim3(256), 0, stream,
                       ows, out);
  } else {
    hipLaunchKernelGGL((tno_conv_kernel<0>), dim3(4096), dim3(64), 0, stream,
                       xT, tT, out);
  }
}